// Round 3
// baseline (230.717 us; speedup 1.0000x reference)
//
#include <hip/hip_runtime.h>
#include <math.h>

#define H 64
// ws layout (floats):
//   [0..63]    z_hist (LSTM final h)
//   [64..319]  64 x float4 fuse params: {base, sc0, sc1, w2}
//   [320]      completion counter (uint, memset to 0 each call)
//   [384..]    edge partials (eb*64), then node partials (nb*64)
#define WS_H 0
#define WS_FUSE 64
#define WS_CNT 320
#define WS_PART 384
#define LOG2E 1.4426950408889634f

__device__ __forceinline__ float fast_sigmoid(float x) {
    float e = exp2f(-LOG2E * x);
    return __builtin_amdgcn_rcpf(1.f + e);
}
__device__ __forceinline__ float fast_tanh(float x) {
    x = fminf(fmaxf(x, -9.f), 9.f);
    float e = exp2f((2.f * LOG2E) * x);
    return (e - 1.f) * __builtin_amdgcn_rcpf(e + 1.f);
}

// ---------------- encoder: relu(X @ W + b) partial column-sums ----------------
template<int K>
__device__ void encode_rows2(const float* __restrict__ X, const float* __restrict__ Wg,
                             const float* __restrict__ bias, int nrows,
                             int blk, int nblk, float* __restrict__ out, int tid,
                             float* __restrict__ xs)
{
    constexpr int TR = 512;                 // rows per LDS tile
    int lane = tid & 63;
    int j0 = (tid >> 6) * 16;               // 16-column slice per wave
    float w[K][16], bi[16], acc[16];
#pragma unroll
    for (int k = 0; k < K; ++k)
#pragma unroll
        for (int jj = 0; jj < 16; ++jj) w[k][jj] = Wg[k * H + j0 + jj];
#pragma unroll
    for (int jj = 0; jj < 16; ++jj) { bi[jj] = bias[j0 + jj]; acc[jj] = 0.f; }

    int ntiles = (nrows + TR - 1) / TR;
    for (int tile = blk; tile < ntiles; tile += nblk) {
        size_t base = (size_t)tile * TR;
        int cnt = nrows - (int)base; if (cnt > TR) cnt = TR;
        int ne = cnt * K;
        __syncthreads();
        const float* Xb = X + base * K;
        int n4 = ne >> 2;
        for (int idx = tid; idx < n4; idx += 256)
            ((float4*)xs)[idx] = ((const float4*)Xb)[idx];
        for (int idx = (n4 << 2) + tid; idx < ne; idx += 256)
            xs[idx] = Xb[idx];
        __syncthreads();
#pragma unroll
        for (int i = 0; i < TR / 64; ++i) {
            int r = i * 64 + lane;
            if (r < cnt) {
                float x[K];
#pragma unroll
                for (int k = 0; k < K; ++k) x[k] = xs[r * K + k];
#pragma unroll
                for (int jj = 0; jj < 16; ++jj) {
                    float t = bi[jj];
#pragma unroll
                    for (int k = 0; k < K; ++k) t = fmaf(x[k], w[k][jj], t);
                    acc[jj] += fmaxf(t, 0.f);
                }
            }
        }
    }
#pragma unroll
    for (int jj = 0; jj < 16; ++jj) {
        float v = acc[jj];
#pragma unroll
        for (int off = 32; off; off >>= 1) v += __shfl_xor(v, off);
        if (lane == jj) out[j0 + jj] = v;
    }
}

// ---------------- finalize (run by the last-finishing block) ----------------
__device__ void finalize_dev(int tid, const float* __restrict__ W1,
                             const float* __restrict__ b1, const float* __restrict__ W2,
                             float inv_n, float inv_e, float inv_denom,
                             int eb, int nb, float* __restrict__ ws, float* __restrict__ fin)
{
    float* tmpe = fin;            // [4][64]
    float* tmpn = fin + 256;      // [4][64]
    float* ctx  = fin + 512;      // [192]
    float* pt   = fin + 704;      // [4][64]
    int q = tid >> 6, j = tid & 63;
    const float* wsp = ws + WS_PART;

    float se = 0.f;
    for (int b = q; b < eb; b += 4) se += wsp[(size_t)b * H + j];
    tmpe[q * H + j] = se;
    float sn = 0.f;
    for (int b = q; b < nb; b += 4) sn += wsp[(size_t)(eb + b) * H + j];
    tmpn[q * H + j] = sn;
    __syncthreads();

    if (tid < H) {
        float s1 = (tmpn[tid] + tmpn[H + tid]) + (tmpn[2 * H + tid] + tmpn[3 * H + tid]);
        float s2 = (tmpe[tid] + tmpe[H + tid]) + (tmpe[2 * H + tid] + tmpe[3 * H + tid]);
        ctx[tid]         = s1 * inv_n;
        ctx[H + tid]     = s2 * inv_e;
        ctx[2 * H + tid] = ws[WS_H + tid];
    }
    __syncthreads();

    float p = 0.f;
#pragma unroll
    for (int kk = 0; kk < 48; ++kk) {
        int k = q * 48 + kk;
        p = fmaf(ctx[k], W1[(size_t)k * H + j], p);
    }
    pt[q * H + j] = p;
    __syncthreads();

    if (tid < H) {
        float bse = b1[tid] + (pt[tid] + pt[H + tid]) + (pt[2 * H + tid] + pt[3 * H + tid]);
        float4 v;
        v.x = bse;
        v.y = W1[(size_t)192 * H + tid] * inv_denom;
        v.z = W1[(size_t)193 * H + tid] * inv_denom;
        v.w = W2[tid];
        ((float4*)(ws + WS_FUSE))[tid] = v;
    }
}

// ---------------- kernel A: block 0 = LSTM, others = encoders; last block finalizes ----------------
__global__ __launch_bounds__(256)
void k_main(const float* __restrict__ node_feats, const float* __restrict__ edge_feats,
            const float* __restrict__ hist,
            const float* __restrict__ node_W, const float* __restrict__ node_b,
            const float* __restrict__ edge_W, const float* __restrict__ edge_b,
            const float* __restrict__ Wih, const float* __restrict__ Whh,
            const float* __restrict__ bih, const float* __restrict__ bhh,
            const float* __restrict__ W1, const float* __restrict__ b1,
            const float* __restrict__ W2,
            float inv_n, float inv_e, float inv_denom,
            int Nn, int Ne, int T, int eb, int nb,
            float* __restrict__ ws)
{
    __shared__ __align__(16) char smem[12800];   // union: edge xs(10240)/node xs(4096)/lstm(12640)/finalize(3840)
    __shared__ unsigned lastflag;
    int tid = threadIdx.x;
    int b = blockIdx.x;

    if (b == 0) {
        // ---- LSTM: wave s owns k-segment [16s,16s+16); lane j owns h[j] ----
        float* pb     = (float*)smem;            // [2][64][20] partial exchange, pad-20 rows
        float* hist_f = (float*)(smem + 10240);  // [T*3]
        int s = tid >> 6, j = tid & 63;
        int kbase = __builtin_amdgcn_readfirstlane((tid >> 6) << 4);  // SGPR 16*s

        float w[4][16];                          // w[g][m] = Whh[(g*64+j)][16s+m]
#pragma unroll
        for (int g = 0; g < 4; ++g) {
            const float* wr = Whh + (size_t)(g * H + j) * H + kbase;
#pragma unroll
            for (int m4 = 0; m4 < 4; ++m4) {
                float4 v = *(const float4*)(wr + 4 * m4);
                w[g][4*m4+0] = v.x; w[g][4*m4+1] = v.y; w[g][4*m4+2] = v.z; w[g][4*m4+3] = v.w;
            }
        }
        float wi0[4], wi1[4], wi2[4], bb[4];
#pragma unroll
        for (int g = 0; g < 4; ++g) {
            int row = g * H + j;
            wi0[g] = Wih[row*3+0]; wi1[g] = Wih[row*3+1]; wi2[g] = Wih[row*3+2];
            bb[g] = bih[row] + bhh[row];
        }
        for (int idx = tid; idx < T * 3; idx += 256) hist_f[idx] = hist[idx];
        float hs[16];
#pragma unroll
        for (int m = 0; m < 16; ++m) hs[m] = 0.f;
        float c = 0.f, h = 0.f;
        __syncthreads();
        float x0 = hist_f[0], x1 = hist_f[1], x2 = hist_f[2];
        __builtin_amdgcn_s_setprio(1);

        for (int t = 0; t < T; ++t) {
            // partial dots for all 4 gates over this wave's k-segment
            float a0 = 0.f, a1 = 0.f, a2 = 0.f, a3 = 0.f;
#pragma unroll
            for (int m = 0; m < 16; ++m) {
                a0 = fmaf(w[0][m], hs[m], a0);
                a1 = fmaf(w[1][m], hs[m], a1);
                a2 = fmaf(w[2][m], hs[m], a2);
                a3 = fmaf(w[3][m], hs[m], a3);
            }
            // bias + Wih·x (same for every wave; folded post-read)
            float xb0 = fmaf(wi2[0], x2, fmaf(wi1[0], x1, fmaf(wi0[0], x0, bb[0])));
            float xb1 = fmaf(wi2[1], x2, fmaf(wi1[1], x1, fmaf(wi0[1], x0, bb[1])));
            float xb2 = fmaf(wi2[2], x2, fmaf(wi1[2], x1, fmaf(wi0[2], x0, bb[2])));
            float xb3 = fmaf(wi2[3], x2, fmaf(wi1[3], x1, fmaf(wi0[3], x0, bb[3])));
            float4 part; part.x = a0; part.y = a1; part.z = a2; part.w = a3;
            *(float4*)(pb + ((size_t)((t & 1) * 64 + j)) * 20 + 4 * s) = part;
            if (t + 1 < T) { x0 = hist_f[3*t+3]; x1 = hist_f[3*t+4]; x2 = hist_f[3*t+5]; }
            __syncthreads();                     // the ONLY barrier per step
            const float* row = pb + ((size_t)((t & 1) * 64 + j)) * 20;
            float4 p0 = *(const float4*)(row + 0);
            float4 p1 = *(const float4*)(row + 4);
            float4 p2 = *(const float4*)(row + 8);
            float4 p3 = *(const float4*)(row + 12);
            float gi = fast_sigmoid((p0.x + p1.x) + (p2.x + p3.x) + xb0);
            float gf = fast_sigmoid((p0.y + p1.y) + (p2.y + p3.y) + xb1);
            float gg = fast_tanh  ((p0.z + p1.z) + (p2.z + p3.z) + xb2);
            float go = fast_sigmoid((p0.w + p1.w) + (p2.w + p3.w) + xb3);
            c = fmaf(gf, c, gi * gg);
            h = go * fast_tanh(c);
            // redistribute own k-segment of h from own wave's lanes (no barrier)
#pragma unroll
            for (int m = 0; m < 16; ++m)
                hs[m] = __int_as_float(__builtin_amdgcn_readlane(__float_as_int(h), kbase + m));
        }
        __builtin_amdgcn_s_setprio(0);
        if (s == 0) ws[WS_H + j] = h;
    } else if (b <= eb) {
        encode_rows2<5>(edge_feats, edge_W, edge_b, Ne, b - 1, eb,
                        ws + WS_PART + (size_t)(b - 1) * H, tid, (float*)smem);
    } else {
        encode_rows2<2>(node_feats, node_W, node_b, Nn, b - 1 - eb, nb,
                        ws + WS_PART + (size_t)(eb + (b - 1 - eb)) * H, tid, (float*)smem);
    }

    // ---- completion counter; last-arriving block runs finalize ----
    __threadfence();                             // release: partials visible device-wide
    if (tid == 0) {
        unsigned prev = atomicAdd((unsigned*)(ws + WS_CNT), 1u);
        lastflag = (prev == (unsigned)(gridDim.x - 1)) ? 1u : 0u;
    }
    __syncthreads();
    if (lastflag) {
        __threadfence();                         // acquire: see all other blocks' partials
        finalize_dev(tid, W1, b1, W2, inv_n, inv_e, inv_denom, eb, nb, ws, (float*)smem);
    }
}

// ---------------- kernel C: per-pair fused MLP score, 8 pairs/thread ----------------
__global__ __launch_bounds__(256)
void k_fuse(const int* __restrict__ pairs, const float* __restrict__ fb2,
            const float* __restrict__ ws, float* __restrict__ out, int P)
{
    __shared__ __align__(16) float4 sf[H];
    int tid = threadIdx.x;
    if (tid < H) sf[tid] = ((const float4*)(ws + WS_FUSE))[tid];
    __syncthreads();

    int i0 = blockIdx.x * 2048 + tid;
    float bias = fb2[0];
    float p0[8], p1[8], sc[8];
#pragma unroll
    for (int q = 0; q < 8; ++q) {
        int i = i0 + q * 256;
        int2 pr = (i < P) ? ((const int2*)pairs)[i] : make_int2(0, 0);
        p0[q] = (float)pr.x; p1[q] = (float)pr.y; sc[q] = bias;
    }
#pragma unroll
    for (int jj = 0; jj < H; ++jj) {
        float4 v = sf[jj];
#pragma unroll
        for (int q = 0; q < 8; ++q) {
            float hh = fmaf(p1[q], v.z, fmaf(p0[q], v.y, v.x));
            sc[q] = fmaf(fmaxf(hh, 0.f), v.w, sc[q]);
        }
    }
#pragma unroll
    for (int q = 0; q < 8; ++q) {
        int i = i0 + q * 256;
        if (i < P) out[i] = sc[q];
    }
}

extern "C" void kernel_launch(void* const* d_in, const int* in_sizes, int n_in,
                              void* d_out, int out_size, void* d_ws, size_t ws_size,
                              hipStream_t stream) {
    const float* node_feats = (const float*)d_in[0];
    const float* edge_feats = (const float*)d_in[1];
    const float* hist       = (const float*)d_in[2];
    const int*   pairs      = (const int*)d_in[3];
    // d_in[4] = N scalar (== node row count)
    const float* node_W = (const float*)d_in[5];
    const float* node_b = (const float*)d_in[6];
    const float* edge_W = (const float*)d_in[7];
    const float* edge_b = (const float*)d_in[8];
    const float* Wih    = (const float*)d_in[9];
    const float* Whh    = (const float*)d_in[10];
    const float* bih    = (const float*)d_in[11];
    const float* bhh    = (const float*)d_in[12];
    const float* W1     = (const float*)d_in[13];
    const float* b1     = (const float*)d_in[14];
    const float* W2     = (const float*)d_in[15];
    const float* b2     = (const float*)d_in[16];

    int Nn = in_sizes[0] / 2;
    int Ne = in_sizes[1] / 5;
    int T  = in_sizes[2] / 3;
    int P  = in_sizes[3] / 2;

    int eb = 1024, nb = 64;
    while ((size_t)(WS_PART + (eb + nb) * H) * sizeof(float) > ws_size && eb > 8) {
        eb >>= 1; if (nb > 4) nb >>= 1;
    }

    float inv_n = (float)(1.0 / (double)Nn);
    float inv_e = (float)(1.0 / (double)Ne);
    float denomf = (float)(Nn - 1) + 1e-9f;
    float inv_denom = 1.0f / denomf;

    float* ws = (float*)d_ws;

    hipMemsetAsync((char*)d_ws + WS_CNT * sizeof(float), 0, sizeof(unsigned), stream);

    k_main<<<1 + eb + nb, 256, 0, stream>>>(
        node_feats, edge_feats, hist, node_W, node_b, edge_W, edge_b,
        Wih, Whh, bih, bhh, W1, b1, W2,
        inv_n, inv_e, inv_denom, Nn, Ne, T, eb, nb, ws);

    int blocksC = (P + 2047) / 2048;
    k_fuse<<<blocksC, 256, 0, stream>>>(pairs, b2, ws, (float*)d_out, P);
}

// Round 4
// 152.672 us; speedup vs baseline: 1.5112x; 1.5112x over previous
//
#include <hip/hip_runtime.h>
#include <math.h>

#define H 64
// ws layout (floats):
//   [0..63]    z_hist (LSTM final h)
//   [64..319]  64 x float4 fuse params: {base, sc0, sc1, w2}
//   [320]      completion counter (uint, memset to 0 each call)
//   [384..]    edge partials (eb*64), then node partials (nb*64)
#define WS_H 0
#define WS_FUSE 64
#define WS_CNT 320
#define WS_PART 384
#define LOG2E 1.4426950408889634f

__device__ __forceinline__ float fast_sigmoid(float x) {
    float e = exp2f(-LOG2E * x);
    return __builtin_amdgcn_rcpf(1.f + e);
}
__device__ __forceinline__ float fast_tanh(float x) {
    x = fminf(fmaxf(x, -9.f), 9.f);
    float e = exp2f((2.f * LOG2E) * x);
    return (e - 1.f) * __builtin_amdgcn_rcpf(e + 1.f);
}

// ---------------- encoder: relu(X @ W + b) partial column-sums ----------------
template<int K>
__device__ void encode_rows2(const float* __restrict__ X, const float* __restrict__ Wg,
                             const float* __restrict__ bias, int nrows,
                             int blk, int nblk, float* __restrict__ out, int tid,
                             float* __restrict__ xs)
{
    constexpr int TR = 512;                 // rows per LDS tile
    int lane = tid & 63;
    int j0 = (tid >> 6) * 16;               // 16-column slice per wave
    float w[K][16], bi[16], acc[16];
#pragma unroll
    for (int k = 0; k < K; ++k)
#pragma unroll
        for (int jj = 0; jj < 16; ++jj) w[k][jj] = Wg[k * H + j0 + jj];
#pragma unroll
    for (int jj = 0; jj < 16; ++jj) { bi[jj] = bias[j0 + jj]; acc[jj] = 0.f; }

    int ntiles = (nrows + TR - 1) / TR;
    for (int tile = blk; tile < ntiles; tile += nblk) {
        size_t base = (size_t)tile * TR;
        int cnt = nrows - (int)base; if (cnt > TR) cnt = TR;
        int ne = cnt * K;
        __syncthreads();
        const float* Xb = X + base * K;
        int n4 = ne >> 2;
        for (int idx = tid; idx < n4; idx += 256)
            ((float4*)xs)[idx] = ((const float4*)Xb)[idx];
        for (int idx = (n4 << 2) + tid; idx < ne; idx += 256)
            xs[idx] = Xb[idx];
        __syncthreads();
#pragma unroll
        for (int i = 0; i < TR / 64; ++i) {
            int r = i * 64 + lane;
            if (r < cnt) {
                float x[K];
#pragma unroll
                for (int k = 0; k < K; ++k) x[k] = xs[r * K + k];
#pragma unroll
                for (int jj = 0; jj < 16; ++jj) {
                    float t = bi[jj];
#pragma unroll
                    for (int k = 0; k < K; ++k) t = fmaf(x[k], w[k][jj], t);
                    acc[jj] += fmaxf(t, 0.f);
                }
            }
        }
    }
#pragma unroll
    for (int jj = 0; jj < 16; ++jj) {
        float v = acc[jj];
#pragma unroll
        for (int off = 32; off; off >>= 1) v += __shfl_xor(v, off);
        if (lane == jj) out[j0 + jj] = v;
    }
}

// ---------------- finalize (run by the last-finishing block) ----------------
__device__ void finalize_dev(int tid, const float* __restrict__ W1,
                             const float* __restrict__ b1, const float* __restrict__ W2,
                             float inv_n, float inv_e, float inv_denom,
                             int eb, int nb, float* __restrict__ ws, float* __restrict__ fin)
{
    float* tmpe = fin;            // [4][64]
    float* tmpn = fin + 256;      // [4][64]
    float* ctx  = fin + 512;      // [192]
    float* pt   = fin + 704;      // [4][64]
    int q = tid >> 6, j = tid & 63;
    const float* wsp = ws + WS_PART;

    float se = 0.f;
    for (int b = q; b < eb; b += 4) se += wsp[(size_t)b * H + j];
    tmpe[q * H + j] = se;
    float sn = 0.f;
    for (int b = q; b < nb; b += 4) sn += wsp[(size_t)(eb + b) * H + j];
    tmpn[q * H + j] = sn;
    __syncthreads();

    if (tid < H) {
        float s1 = (tmpn[tid] + tmpn[H + tid]) + (tmpn[2 * H + tid] + tmpn[3 * H + tid]);
        float s2 = (tmpe[tid] + tmpe[H + tid]) + (tmpe[2 * H + tid] + tmpe[3 * H + tid]);
        ctx[tid]         = s1 * inv_n;
        ctx[H + tid]     = s2 * inv_e;
        ctx[2 * H + tid] = ws[WS_H + tid];
    }
    __syncthreads();

    float p = 0.f;
#pragma unroll
    for (int kk = 0; kk < 48; ++kk) {
        int k = q * 48 + kk;
        p = fmaf(ctx[k], W1[(size_t)k * H + j], p);
    }
    pt[q * H + j] = p;
    __syncthreads();

    if (tid < H) {
        float bse = b1[tid] + (pt[tid] + pt[H + tid]) + (pt[2 * H + tid] + pt[3 * H + tid]);
        float4 v;
        v.x = bse;
        v.y = W1[(size_t)192 * H + tid] * inv_denom;
        v.z = W1[(size_t)193 * H + tid] * inv_denom;
        v.w = W2[tid];
        ((float4*)(ws + WS_FUSE))[tid] = v;
    }
}

// ---------------- kernel A: block 0 = LSTM, others = encoders; last block finalizes ----------------
__global__ __launch_bounds__(256, 2)   // min 2 waves/EU -> VGPR cap 256: NO SPILLS (r3: 76 VGPR = spilled arrays)
void k_main(const float* __restrict__ node_feats, const float* __restrict__ edge_feats,
            const float* __restrict__ hist,
            const float* __restrict__ node_W, const float* __restrict__ node_b,
            const float* __restrict__ edge_W, const float* __restrict__ edge_b,
            const float* __restrict__ Wih, const float* __restrict__ Whh,
            const float* __restrict__ bih, const float* __restrict__ bhh,
            const float* __restrict__ W1, const float* __restrict__ b1,
            const float* __restrict__ W2,
            float inv_n, float inv_e, float inv_denom,
            int Nn, int Ne, int T, int eb, int nb,
            float* __restrict__ ws)
{
    __shared__ __align__(16) char smem[12800];   // union: edge xs(10240)/node xs(4096)/lstm(12640)/finalize(3840)
    __shared__ unsigned lastflag;
    int tid = threadIdx.x;
    int b = blockIdx.x;

    if (b == 0) {
        // ---- LSTM: wave s owns k-segment [16s,16s+16); lane j owns h[j]; 1 barrier/step ----
        float* pb     = (float*)smem;            // [2][64][20] partial exchange, pad-20 rows
        float* hist_f = (float*)(smem + 10240);  // [T*3]
        int s = tid >> 6, j = tid & 63;
        int kbase = __builtin_amdgcn_readfirstlane((tid >> 6) << 4);  // SGPR 16*s

        float w[4][16];                          // w[g][m] = Whh[(g*64+j)][16s+m]
#pragma unroll
        for (int g = 0; g < 4; ++g) {
            const float* wr = Whh + (size_t)(g * H + j) * H + kbase;
#pragma unroll
            for (int m4 = 0; m4 < 4; ++m4) {
                float4 v = *(const float4*)(wr + 4 * m4);
                w[g][4*m4+0] = v.x; w[g][4*m4+1] = v.y; w[g][4*m4+2] = v.z; w[g][4*m4+3] = v.w;
            }
        }
        float wi0[4], wi1[4], wi2[4], bb[4];
#pragma unroll
        for (int g = 0; g < 4; ++g) {
            int row = g * H + j;
            wi0[g] = Wih[row*3+0]; wi1[g] = Wih[row*3+1]; wi2[g] = Wih[row*3+2];
            bb[g] = bih[row] + bhh[row];
        }
        for (int idx = tid; idx < T * 3; idx += 256) hist_f[idx] = hist[idx];
        float hs[16];
#pragma unroll
        for (int m = 0; m < 16; ++m) hs[m] = 0.f;
        float c = 0.f, h = 0.f;
        __syncthreads();
        float x0 = hist_f[0], x1 = hist_f[1], x2 = hist_f[2];
        __builtin_amdgcn_s_setprio(1);

        for (int t = 0; t < T; ++t) {
            // partial dots for all 4 gates over this wave's k-segment
            float a0 = 0.f, a1 = 0.f, a2 = 0.f, a3 = 0.f;
#pragma unroll
            for (int m = 0; m < 16; ++m) {
                a0 = fmaf(w[0][m], hs[m], a0);
                a1 = fmaf(w[1][m], hs[m], a1);
                a2 = fmaf(w[2][m], hs[m], a2);
                a3 = fmaf(w[3][m], hs[m], a3);
            }
            float4 part; part.x = a0; part.y = a1; part.z = a2; part.w = a3;
            *(float4*)(pb + ((size_t)((t & 1) * 64 + j)) * 20 + 4 * s) = part;
            // bias + Wih·x folded into the LDS-write shadow (independent of hs)
            float xb0 = fmaf(wi2[0], x2, fmaf(wi1[0], x1, fmaf(wi0[0], x0, bb[0])));
            float xb1 = fmaf(wi2[1], x2, fmaf(wi1[1], x1, fmaf(wi0[1], x0, bb[1])));
            float xb2 = fmaf(wi2[2], x2, fmaf(wi1[2], x1, fmaf(wi0[2], x0, bb[2])));
            float xb3 = fmaf(wi2[3], x2, fmaf(wi1[3], x1, fmaf(wi0[3], x0, bb[3])));
            if (t + 1 < T) { x0 = hist_f[3*t+3]; x1 = hist_f[3*t+4]; x2 = hist_f[3*t+5]; }
            __syncthreads();                     // the ONLY barrier per step
            const float* row = pb + ((size_t)((t & 1) * 64 + j)) * 20;
            float4 p0 = *(const float4*)(row + 0);
            float4 p1 = *(const float4*)(row + 4);
            float4 p2 = *(const float4*)(row + 8);
            float4 p3 = *(const float4*)(row + 12);
            float gi = fast_sigmoid((p0.x + p1.x) + (p2.x + p3.x) + xb0);
            float gf = fast_sigmoid((p0.y + p1.y) + (p2.y + p3.y) + xb1);
            float gg = fast_tanh  ((p0.z + p1.z) + (p2.z + p3.z) + xb2);
            float go = fast_sigmoid((p0.w + p1.w) + (p2.w + p3.w) + xb3);
            c = fmaf(gf, c, gi * gg);
            h = go * fast_tanh(c);
            // redistribute own k-segment of h from own wave's lanes (register-only)
#pragma unroll
            for (int m = 0; m < 16; ++m)
                hs[m] = __int_as_float(__builtin_amdgcn_readlane(__float_as_int(h), kbase + m));
        }
        __builtin_amdgcn_s_setprio(0);
        if (s == 0) ws[WS_H + j] = h;
    } else if (b <= eb) {
        encode_rows2<5>(edge_feats, edge_W, edge_b, Ne, b - 1, eb,
                        ws + WS_PART + (size_t)(b - 1) * H, tid, (float*)smem);
    } else {
        encode_rows2<2>(node_feats, node_W, node_b, Nn, b - 1 - eb, nb,
                        ws + WS_PART + (size_t)(eb + (b - 1 - eb)) * H, tid, (float*)smem);
    }

    // ---- completion counter; last-arriving block runs finalize ----
    __threadfence();                             // release: partials visible device-wide
    if (tid == 0) {
        unsigned prev = atomicAdd((unsigned*)(ws + WS_CNT), 1u);
        lastflag = (prev == (unsigned)(gridDim.x - 1)) ? 1u : 0u;
    }
    __syncthreads();
    if (lastflag) {
        __threadfence();                         // acquire: see all other blocks' partials
        finalize_dev(tid, W1, b1, W2, inv_n, inv_e, inv_denom, eb, nb, ws, (float*)smem);
    }
}

// ---------------- kernel C: per-pair fused MLP score, 8 pairs/thread ----------------
__global__ __launch_bounds__(256)
void k_fuse(const int* __restrict__ pairs, const float* __restrict__ fb2,
            const float* __restrict__ ws, float* __restrict__ out, int P)
{
    __shared__ __align__(16) float4 sf[H];
    int tid = threadIdx.x;
    if (tid < H) sf[tid] = ((const float4*)(ws + WS_FUSE))[tid];
    __syncthreads();

    int i0 = blockIdx.x * 2048 + tid;
    float bias = fb2[0];
    float p0[8], p1[8], sc[8];
#pragma unroll
    for (int q = 0; q < 8; ++q) {
        int i = i0 + q * 256;
        int2 pr = (i < P) ? ((const int2*)pairs)[i] : make_int2(0, 0);
        p0[q] = (float)pr.x; p1[q] = (float)pr.y; sc[q] = bias;
    }
#pragma unroll
    for (int jj = 0; jj < H; ++jj) {
        float4 v = sf[jj];
#pragma unroll
        for (int q = 0; q < 8; ++q) {
            float hh = fmaf(p1[q], v.z, fmaf(p0[q], v.y, v.x));
            sc[q] = fmaf(fmaxf(hh, 0.f), v.w, sc[q]);
        }
    }
#pragma unroll
    for (int q = 0; q < 8; ++q) {
        int i = i0 + q * 256;
        if (i < P) out[i] = sc[q];
    }
}

extern "C" void kernel_launch(void* const* d_in, const int* in_sizes, int n_in,
                              void* d_out, int out_size, void* d_ws, size_t ws_size,
                              hipStream_t stream) {
    const float* node_feats = (const float*)d_in[0];
    const float* edge_feats = (const float*)d_in[1];
    const float* hist       = (const float*)d_in[2];
    const int*   pairs      = (const int*)d_in[3];
    // d_in[4] = N scalar (== node row count)
    const float* node_W = (const float*)d_in[5];
    const float* node_b = (const float*)d_in[6];
    const float* edge_W = (const float*)d_in[7];
    const float* edge_b = (const float*)d_in[8];
    const float* Wih    = (const float*)d_in[9];
    const float* Whh    = (const float*)d_in[10];
    const float* bih    = (const float*)d_in[11];
    const float* bhh    = (const float*)d_in[12];
    const float* W1     = (const float*)d_in[13];
    const float* b1     = (const float*)d_in[14];
    const float* W2     = (const float*)d_in[15];
    const float* b2     = (const float*)d_in[16];

    int Nn = in_sizes[0] / 2;
    int Ne = in_sizes[1] / 5;
    int T  = in_sizes[2] / 3;
    int P  = in_sizes[3] / 2;

    // grid sized so ALL blocks are co-resident at 2 blocks/CU (512 slots):
    // 1 LSTM + 448 edge + 48 node = 497 blocks -> static partition has no tail.
    int eb = 448, nb = 48;
    while ((size_t)(WS_PART + (eb + nb) * H) * sizeof(float) > ws_size && eb > 8) {
        eb >>= 1; if (nb > 4) nb >>= 1;
    }

    float inv_n = (float)(1.0 / (double)Nn);
    float inv_e = (float)(1.0 / (double)Ne);
    float denomf = (float)(Nn - 1) + 1e-9f;
    float inv_denom = 1.0f / denomf;

    float* ws = (float*)d_ws;

    hipMemsetAsync((char*)d_ws + WS_CNT * sizeof(float), 0, sizeof(unsigned), stream);

    k_main<<<1 + eb + nb, 256, 0, stream>>>(
        node_feats, edge_feats, hist, node_W, node_b, edge_W, edge_b,
        Wih, Whh, bih, bhh, W1, b1, W2,
        inv_n, inv_e, inv_denom, Nn, Ne, T, eb, nb, ws);

    int blocksC = (P + 2047) / 2048;
    k_fuse<<<blocksC, 256, 0, stream>>>(pairs, b2, ws, (float*)d_out, P);
}